// Round 8
// baseline (80.592 us; speedup 1.0000x reference)
//
#include <hip/hip_runtime.h>

#define NB 8
#define NN 2048
#define FIN 256
#define FOUT 128

typedef __attribute__((ext_vector_type(8))) short short8;
typedef __attribute__((ext_vector_type(4))) float f32x4;
typedef __attribute__((ext_vector_type(4))) int i32x4;

static __device__ __forceinline__ unsigned short f2bf(float f) {
    unsigned int u = __float_as_uint(f);
    u += 0x7fffu + ((u >> 16) & 1u);
    return (unsigned short)(u >> 16);
}

// K1: unchanged (verified since R1). Wh = h@W fp32; emits s1/s2 + WhPV bf16 fragments.
// WhPV layout per 64-j chunk: [kt(2)][nt(8)][lane(64)][i(8)],
//   element = Wh[j0 + 32*kt + 8*(lane>>4) + i][16*nt + (lane&15)]   (sigma(g,i)=8g+i)
__global__ __launch_bounds__(256) void gat_prep(
    const float* __restrict__ h, const float* __restrict__ W, const float* __restrict__ a,
    unsigned short* __restrict__ whpv, float* __restrict__ s1g, float* __restrict__ s2g)
{
    __shared__ __align__(16) float hT[64 * FIN];
    __shared__ __align__(16) unsigned short pvs[8192];
    const int t = threadIdx.x;
    const int bx = blockIdx.x;
    const int b = bx >> 5;
    const int jt = bx & 31;
    const int j0 = jt * 64;

    const float* hsrc = h + ((size_t)b * NN + j0) * FIN;
    #pragma unroll
    for (int p = 0; p < 16; ++p) {
        int idx = p * 256 + t;
        *(f32x4*)&hT[idx * 4] = *(const f32x4*)&hsrc[idx * 4];
    }
    __syncthreads();

    const int cg = t & 31;
    const int rg = t >> 5;
    float acc[8][4];
    #pragma unroll
    for (int r = 0; r < 8; ++r)
        #pragma unroll
        for (int q = 0; q < 4; ++q) acc[r][q] = 0.f;

    for (int f = 0; f < FIN; f += 4) {
        f32x4 wv[4];
        #pragma unroll
        for (int q = 0; q < 4; ++q) wv[q] = *(const f32x4*)&W[(f + q) * FOUT + cg * 4];
        #pragma unroll
        for (int r = 0; r < 8; ++r) {
            f32x4 hv = *(const f32x4*)&hT[(rg * 8 + r) * FIN + f];
            #pragma unroll
            for (int q = 0; q < 4; ++q) {
                acc[r][0] += hv[q] * wv[q][0];
                acc[r][1] += hv[q] * wv[q][1];
                acc[r][2] += hv[q] * wv[q][2];
                acc[r][3] += hv[q] * wv[q][3];
            }
        }
    }

    f32x4 a1v = *(const f32x4*)&a[cg * 4];
    f32x4 a2v = *(const f32x4*)&a[FOUT + cg * 4];
    #pragma unroll
    for (int r = 0; r < 8; ++r) {
        float p1 = acc[r][0]*a1v[0] + acc[r][1]*a1v[1] + acc[r][2]*a1v[2] + acc[r][3]*a1v[3];
        float p2 = acc[r][0]*a2v[0] + acc[r][1]*a2v[1] + acc[r][2]*a2v[2] + acc[r][3]*a2v[3];
        #pragma unroll
        for (int m = 16; m >= 1; m >>= 1) {
            p1 += __shfl_xor(p1, m, 64);
            p2 += __shfl_xor(p2, m, 64);
        }
        if (cg == 0) {
            s1g[b * NN + j0 + rg * 8 + r] = p1;
            s2g[b * NN + j0 + rg * 8 + r] = p2;
        }
    }

    #pragma unroll
    for (int r = 0; r < 8; ++r) {
        int jl = rg * 8 + r;
        int kt = jl >> 5, j5 = jl & 31, g = j5 >> 3, i = j5 & 7;
        #pragma unroll
        for (int q = 0; q < 4; ++q) {
            int c = cg * 4 + q;
            int lane = g * 16 + (c & 15);
            int nt = c >> 4;
            pvs[((kt * 8 + nt) * 64 + lane) * 8 + i] = f2bf(acc[r][q]);
        }
    }
    __syncthreads();
    unsigned short* dst = whpv + (size_t)(b * 32 + jt) * 8192;
    #pragma unroll
    for (int p = 0; p < 4; ++p) {
        int idx = p * 2048 + t * 8;
        *(short8*)&dst[idx] = *(const short8*)&pvs[idx];
    }
}

// Compute one A-fragment (8 bf16 P values, sigma(g,i)=8g+i) in registers.
// ALO/AHI: 8 adj ints; S2LO/S2HI: 8 s2 floats; S1: row score.
#define MAKE_PA(PA, SSUM, ALO, AHI, S2LO, S2HI, S1)                        \
    do {                                                                   \
        float p0_, p1_, p2_, p3_, p4_, p5_, p6_, p7_;                      \
        float e_;                                                          \
        e_ = (S1) + S2LO[0]; e_ = fmaxf(e_, 0.2f * e_);                    \
        p0_ = (ALO.x > 0) ? __expf(e_) : 0.f;                              \
        e_ = (S1) + S2LO[1]; e_ = fmaxf(e_, 0.2f * e_);                    \
        p1_ = (ALO.y > 0) ? __expf(e_) : 0.f;                              \
        e_ = (S1) + S2LO[2]; e_ = fmaxf(e_, 0.2f * e_);                    \
        p2_ = (ALO.z > 0) ? __expf(e_) : 0.f;                              \
        e_ = (S1) + S2LO[3]; e_ = fmaxf(e_, 0.2f * e_);                    \
        p3_ = (ALO.w > 0) ? __expf(e_) : 0.f;                              \
        e_ = (S1) + S2HI[0]; e_ = fmaxf(e_, 0.2f * e_);                    \
        p4_ = (AHI.x > 0) ? __expf(e_) : 0.f;                              \
        e_ = (S1) + S2HI[1]; e_ = fmaxf(e_, 0.2f * e_);                    \
        p5_ = (AHI.y > 0) ? __expf(e_) : 0.f;                              \
        e_ = (S1) + S2HI[2]; e_ = fmaxf(e_, 0.2f * e_);                    \
        p6_ = (AHI.z > 0) ? __expf(e_) : 0.f;                              \
        e_ = (S1) + S2HI[3]; e_ = fmaxf(e_, 0.2f * e_);                    \
        p7_ = (AHI.w > 0) ? __expf(e_) : 0.f;                              \
        SSUM += ((p0_ + p1_) + (p2_ + p3_)) + ((p4_ + p5_) + (p6_ + p7_)); \
        union { unsigned int w_[4]; short8 s_; } u_;                       \
        u_.w_[0] = (unsigned int)f2bf(p0_) | ((unsigned int)f2bf(p1_) << 16); \
        u_.w_[1] = (unsigned int)f2bf(p2_) | ((unsigned int)f2bf(p3_) << 16); \
        u_.w_[2] = (unsigned int)f2bf(p4_) | ((unsigned int)f2bf(p5_) << 16); \
        u_.w_[3] = (unsigned int)f2bf(p6_) | ((unsigned int)f2bf(p7_) << 16); \
        PA = u_.s_;                                                        \
    } while (0)

// K2 v7: barrier-free. Each wave owns 32 rows x 512 j (quarter of the j-range):
// P-fragments computed in registers (A-layout), adj per-lane nontemporal, B frags
// direct from XCD-local L2, MFMA immediately. No loop barriers; partials from the
// 4 j-quarter waves combined through LDS at the end (sums add exactly).
__global__ __launch_bounds__(256, 2) void gat_main(
    const int* __restrict__ adj, const unsigned short* __restrict__ whpv,
    const float* __restrict__ s1g, const float* __restrict__ s2g, float* __restrict__ out)
{
    __shared__ __align__(16) float s2s[NN];              // 8 KB: full s2 row
    __shared__ __align__(16) float part[4][16][64][4];   // 64 KB: partial accs
    __shared__ float Sp[4][2][16];                       // row-sum partials

    const int t = threadIdx.x;
    const int bx = blockIdx.x;
    const int b  = bx & 7;            // XCD affinity: whpv[b] L2-resident
    const int i0 = (bx >> 3) * 32;    // 64 i-tiles per batch

    const int jw   = t >> 6;   // j-quarter 0..3
    const int lane = t & 63;
    const int g    = lane >> 4;
    const int c15  = lane & 15;

    // stage s2 (whole 2048-row) into LDS
    const float* s2b = s2g + b * NN;
    *(f32x4*)&s2s[t * 8]     = *(const f32x4*)&s2b[t * 8];
    *(f32x4*)&s2s[t * 8 + 4] = *(const f32x4*)&s2b[t * 8 + 4];
    __syncthreads();

    const float s1r0 = s1g[b * NN + i0 + c15];
    const float s1r1 = s1g[b * NN + i0 + 16 + c15];

    const int* ar0 = adj + ((size_t)b * NN + (i0 + c15)) * NN;
    const int* ar1 = adj + ((size_t)b * NN + (i0 + 16 + c15)) * NN;
    const unsigned short* whb = whpv + (size_t)b * 32 * 8192;

    f32x4 acc0[8], acc1[8];
    #pragma unroll
    for (int nt = 0; nt < 8; ++nt) {
        acc0[nt] = (f32x4){0.f, 0.f, 0.f, 0.f};
        acc1[nt] = (f32x4){0.f, 0.f, 0.f, 0.f};
    }
    float ssum0 = 0.f, ssum1 = 0.f;

    // depth-1 adj prefetch (8 x i32x4 = rows {r0,r1} x kt {0,1} x {lo,hi})
    i32x4 an0, an1, an2, an3, an4, an5, an6, an7;
    {
        const size_t jb = (size_t)(jw * 8) * 64;
        const int o = 8 * g;
        an0 = __builtin_nontemporal_load((const i32x4*)(ar0 + jb + o));
        an1 = __builtin_nontemporal_load((const i32x4*)(ar0 + jb + o + 4));
        an2 = __builtin_nontemporal_load((const i32x4*)(ar0 + jb + 32 + o));
        an3 = __builtin_nontemporal_load((const i32x4*)(ar0 + jb + 32 + o + 4));
        an4 = __builtin_nontemporal_load((const i32x4*)(ar1 + jb + o));
        an5 = __builtin_nontemporal_load((const i32x4*)(ar1 + jb + o + 4));
        an6 = __builtin_nontemporal_load((const i32x4*)(ar1 + jb + 32 + o));
        an7 = __builtin_nontemporal_load((const i32x4*)(ar1 + jb + 32 + o + 4));
    }

    #pragma unroll 1
    for (int c = 0; c < 8; ++c) {
        const int jcg = jw * 8 + c;

        // consume prefetched adj
        i32x4 aj0 = an0, aj1 = an1, aj2 = an2, aj3 = an3;
        i32x4 aj4 = an4, aj5 = an5, aj6 = an6, aj7 = an7;

        // issue next-chunk adj prefetch (wraps harmlessly)
        {
            const int cn = (c + 1) & 7;
            const size_t jb = (size_t)(jw * 8 + cn) * 64;
            const int o = 8 * g;
            an0 = __builtin_nontemporal_load((const i32x4*)(ar0 + jb + o));
            an1 = __builtin_nontemporal_load((const i32x4*)(ar0 + jb + o + 4));
            an2 = __builtin_nontemporal_load((const i32x4*)(ar0 + jb + 32 + o));
            an3 = __builtin_nontemporal_load((const i32x4*)(ar0 + jb + 32 + o + 4));
            an4 = __builtin_nontemporal_load((const i32x4*)(ar1 + jb + o));
            an5 = __builtin_nontemporal_load((const i32x4*)(ar1 + jb + o + 4));
            an6 = __builtin_nontemporal_load((const i32x4*)(ar1 + jb + 32 + o));
            an7 = __builtin_nontemporal_load((const i32x4*)(ar1 + jb + 32 + o + 4));
        }

        // issue all 16 B-fragment loads (L2) before P-compute — latency hides under exp
        const unsigned short* wf = whb + (size_t)jcg * 8192 + lane * 8;
        short8 bk0[8], bk1[8];
        #pragma unroll
        for (int nt = 0; nt < 8; ++nt) bk0[nt] = *(const short8*)(wf + (0 * 8 + nt) * 512);
        #pragma unroll
        for (int nt = 0; nt < 8; ++nt) bk1[nt] = *(const short8*)(wf + (1 * 8 + nt) * 512);

        // s2 for this chunk (LDS, broadcast within 16-lane groups)
        const int sb = jcg * 64 + 8 * g;
        f32x4 s2k0a = *(const f32x4*)&s2s[sb];
        f32x4 s2k0b = *(const f32x4*)&s2s[sb + 4];
        f32x4 s2k1a = *(const f32x4*)&s2s[sb + 32];
        f32x4 s2k1b = *(const f32x4*)&s2s[sb + 36];

        // P fragments in registers
        short8 pa00, pa01, pa10, pa11;
        MAKE_PA(pa00, ssum0, aj0, aj1, s2k0a, s2k0b, s1r0);
        MAKE_PA(pa01, ssum0, aj2, aj3, s2k1a, s2k1b, s1r0);
        MAKE_PA(pa10, ssum1, aj4, aj5, s2k0a, s2k0b, s1r1);
        MAKE_PA(pa11, ssum1, aj6, aj7, s2k1a, s2k1b, s1r1);

        #pragma unroll
        for (int nt = 0; nt < 8; ++nt) {
            acc0[nt] = __builtin_amdgcn_mfma_f32_16x16x32_bf16(pa00, bk0[nt], acc0[nt], 0, 0, 0);
            acc1[nt] = __builtin_amdgcn_mfma_f32_16x16x32_bf16(pa10, bk0[nt], acc1[nt], 0, 0, 0);
            acc0[nt] = __builtin_amdgcn_mfma_f32_16x16x32_bf16(pa01, bk1[nt], acc0[nt], 0, 0, 0);
            acc1[nt] = __builtin_amdgcn_mfma_f32_16x16x32_bf16(pa11, bk1[nt], acc1[nt], 0, 0, 0);
        }
    }

    // write partials to LDS
    #pragma unroll
    for (int nt = 0; nt < 8; ++nt) {
        *(f32x4*)&part[jw][nt][lane][0]     = acc0[nt];
        *(f32x4*)&part[jw][8 + nt][lane][0] = acc1[nt];
    }
    // row-sum partials: reduce over the 4 g-lanes per row
    {
        float v = ssum0;
        v += __shfl_xor(v, 16, 64);
        v += __shfl_xor(v, 32, 64);
        if (g == 0) Sp[jw][0][c15] = v;
        float u = ssum1;
        u += __shfl_xor(u, 16, 64);
        u += __shfl_xor(u, 32, 64);
        if (g == 0) Sp[jw][1][c15] = u;
    }
    __syncthreads();

    // final reduce: wave jw owns frags [4*jw .. 4*jw+3]; mt = jw>>1, ntb = (jw&1)*4
    const int mt  = jw >> 1;
    const int ntb = (jw & 1) * 4;
    float inv[4];
    #pragma unroll
    for (int q = 0; q < 4; ++q) {
        int row = g * 4 + q;
        float sd = Sp[0][mt][row] + Sp[1][mt][row] + Sp[2][mt][row] + Sp[3][mt][row];
        inv[q] = 1.0f / sd;
    }
    float* ob = out + ((size_t)b * NN + i0) * FOUT;
    #pragma unroll
    for (int u = 0; u < 4; ++u) {
        const int fi = mt * 8 + ntb + u;
        f32x4 v0 = *(const f32x4*)&part[0][fi][lane][0];
        f32x4 v1 = *(const f32x4*)&part[1][fi][lane][0];
        f32x4 v2 = *(const f32x4*)&part[2][fi][lane][0];
        f32x4 v3 = *(const f32x4*)&part[3][fi][lane][0];
        f32x4 s = (v0 + v1) + (v2 + v3);
        const int col = (ntb + u) * 16 + c15;
        #pragma unroll
        for (int q = 0; q < 4; ++q) {
            int row = mt * 16 + g * 4 + q;
            ob[(size_t)row * FOUT + col] = s[q] * inv[q];
        }
    }
}

extern "C" void kernel_launch(void* const* d_in, const int* in_sizes, int n_in,
                              void* d_out, int out_size, void* d_ws, size_t ws_size,
                              hipStream_t stream) {
    (void)in_sizes; (void)n_in; (void)out_size; (void)ws_size;
    const float* h   = (const float*)d_in[0];
    const int*   adj = (const int*)d_in[1];
    const float* W   = (const float*)d_in[2];
    const float* a   = (const float*)d_in[3];
    float* out = (float*)d_out;

    unsigned short* whpv = (unsigned short*)d_ws;                               // 4 MB
    float* s1g = (float*)((char*)d_ws + (4u << 20));                            // 64 KB
    float* s2g = (float*)((char*)d_ws + (4u << 20) + (64u << 10));              // 64 KB

    gat_prep<<<dim3(256), dim3(256), 0, stream>>>(h, W, a, whpv, s1g, s2g);
    gat_main<<<dim3(512), dim3(256), 0, stream>>>(adj, whpv, s1g, s2g, out);
}